// Round 1
// baseline (2875.598 us; speedup 1.0000x reference)
//
#include <hip/hip_runtime.h>

#define NCH 64

// ---------- degree / normalization ----------
__global__ void deg_init_kernel(float* __restrict__ deg, int n) {
    int i = blockIdx.x * blockDim.x + threadIdx.x;
    if (i < n) deg[i] = 1.0f;   // self-loop
}

__global__ void deg_count_kernel(const int* __restrict__ dst, float* __restrict__ deg, int ne) {
    int e = blockIdx.x * blockDim.x + threadIdx.x;
    if (e < ne) atomicAdd(&deg[dst[e]], 1.0f);
}

__global__ void dinv_kernel(float* __restrict__ deg, int n) {
    int i = blockIdx.x * blockDim.x + threadIdx.x;
    if (i < n) deg[i] = rsqrtf(deg[i]);   // deg >= 1 always
}

// ---------- dense 64x64 linear: H = (relu?)(X) @ W ----------
template<bool RELU>
__global__ void gemm64_kernel(const float* __restrict__ X, const float* __restrict__ W,
                              float* __restrict__ H, int n) {
    __shared__ float Ws[NCH * NCH];
    int t = threadIdx.x;
    for (int i = t; i < NCH * NCH; i += blockDim.x) Ws[i] = W[i];
    __syncthreads();
    int row = blockIdx.x * blockDim.x + t;
    if (row >= n) return;
    const float4* xr = (const float4*)(X + (long long)row * NCH);
    float acc[NCH];
#pragma unroll
    for (int c = 0; c < NCH; ++c) acc[c] = 0.f;
#pragma unroll
    for (int k4 = 0; k4 < NCH / 4; ++k4) {
        float4 xv = xr[k4];
        if (RELU) {
            xv.x = fmaxf(xv.x, 0.f); xv.y = fmaxf(xv.y, 0.f);
            xv.z = fmaxf(xv.z, 0.f); xv.w = fmaxf(xv.w, 0.f);
        }
        float xs[4] = {xv.x, xv.y, xv.z, xv.w};
#pragma unroll
        for (int j = 0; j < 4; ++j) {
            int k = k4 * 4 + j;
#pragma unroll
            for (int c = 0; c < NCH; ++c)
                acc[c] = fmaf(xs[j], Ws[k * NCH + c], acc[c]);  // uniform LDS read -> broadcast
        }
    }
    float4* hr = (float4*)(H + (long long)row * NCH);
#pragma unroll
    for (int c4 = 0; c4 < NCH / 4; ++c4)
        hr[c4] = make_float4(acc[4 * c4], acc[4 * c4 + 1], acc[4 * c4 + 2], acc[4 * c4 + 3]);
}

// ---------- out[i,:] = b + dinv[i]^2 * H[i,:]  (bias + self-loop, full overwrite) ----------
__global__ void init_out_kernel(const float* __restrict__ H, const float* __restrict__ dinv,
                                const float* __restrict__ b, float* __restrict__ out, int n) {
    int tid = blockIdx.x * blockDim.x + threadIdx.x;
    int i = tid >> 4;
    int c4 = (tid & 15) * 4;
    if (i >= n) return;
    float di = dinv[i];
    float w = di * di;
    float4 hv = *(const float4*)(H + (long long)i * NCH + c4);
    float4 bv = *(const float4*)(b + c4);
    *(float4*)(out + (long long)i * NCH + c4) =
        make_float4(bv.x + w * hv.x, bv.y + w * hv.y, bv.z + w * hv.z, bv.w + w * hv.w);
}

// ---------- edge scatter: out[dst,:] += dinv[s]*dinv[d] * H[src,:] ----------
__global__ void scatter_kernel(const float* __restrict__ H, const int* __restrict__ src,
                               const int* __restrict__ dst, const float* __restrict__ dinv,
                               float* __restrict__ out, int ne) {
    int tid = blockIdx.x * blockDim.x + threadIdx.x;
    int e = tid >> 4;
    int c4 = (tid & 15) * 4;
    if (e >= ne) return;
    int s = src[e];
    int d = dst[e];
    float nrm = dinv[s] * dinv[d];
    float4 hv = *(const float4*)(H + (long long)s * NCH + c4);
    float* op = out + (long long)d * NCH + c4;
    atomicAdd(op + 0, hv.x * nrm);
    atomicAdd(op + 1, hv.y * nrm);
    atomicAdd(op + 2, hv.z * nrm);
    atomicAdd(op + 3, hv.w * nrm);
}

extern "C" void kernel_launch(void* const* d_in, const int* in_sizes, int n_in,
                              void* d_out, int out_size, void* d_ws, size_t ws_size,
                              hipStream_t stream) {
    const float* x  = (const float*)d_in[0];
    const int*   ei = (const int*)d_in[1];
    const float* W1 = (const float*)d_in[2];
    const float* b1 = (const float*)d_in[3];
    const float* W2 = (const float*)d_in[4];
    const float* b2 = (const float*)d_in[5];
    const int n  = in_sizes[0] / NCH;   // 100000
    const int ne = in_sizes[1] / 2;     // 1600000
    const int* src = ei;
    const int* dst = ei + ne;
    float* out = (float*)d_out;

    char* ws = (char*)d_ws;
    float* dinv = (float*)ws;                                   // n floats (400 KB)
    size_t featBytes = (size_t)n * NCH * sizeof(float);         // 25.6 MB, 256B-aligned
    float* bufA = (float*)(ws + 512 * 1024);                    // h (hW result)
    float* bufB = (float*)(ws + 512 * 1024 + featBytes);        // aggregated layer-1 output

    const int blk = 256;
    const int gN  = (n + blk - 1) / blk;
    const int gE  = (ne + blk - 1) / blk;
    const int gN16 = (n * 16 + blk - 1) / blk;
    const int gE16 = (int)(((long long)ne * 16 + blk - 1) / blk);

    // normalization (shared by both layers)
    deg_init_kernel<<<gN, blk, 0, stream>>>(dinv, n);
    deg_count_kernel<<<gE, blk, 0, stream>>>(dst, dinv, ne);
    dinv_kernel<<<gN, blk, 0, stream>>>(dinv, n);

    // layer 1
    gemm64_kernel<false><<<gN, blk, 0, stream>>>(x, W1, bufA, n);
    init_out_kernel<<<gN16, blk, 0, stream>>>(bufA, dinv, b1, bufB, n);
    scatter_kernel<<<gE16, blk, 0, stream>>>(bufA, src, dst, dinv, bufB, ne);

    // layer 2 (relu fused into GEMM load)
    gemm64_kernel<true><<<gN, blk, 0, stream>>>(bufB, W2, bufA, n);
    init_out_kernel<<<gN16, blk, 0, stream>>>(bufA, dinv, b2, out, n);
    scatter_kernel<<<gE16, blk, 0, stream>>>(bufA, src, dst, dinv, out, ne);
}

// Round 2
// 415.360 us; speedup vs baseline: 6.9231x; 6.9231x over previous
//
#include <hip/hip_runtime.h>

#define NCH 64
#define SCAN_BLK 1024

// ---------------- CSR build ----------------
__global__ void zero_kernel(int* __restrict__ p, int n) {
    int i = blockIdx.x * blockDim.x + threadIdx.x;
    if (i < n) p[i] = 0;
}

__global__ void hist_kernel(const int* __restrict__ dst, int* __restrict__ cnt, int ne) {
    int e = blockIdx.x * blockDim.x + threadIdx.x;
    if (e < ne) atomicAdd(&cnt[dst[e]], 1);
}

// per-block exclusive scan; excl gets in-block exclusive prefix, blockSums[b] = block total
__global__ void scan1_kernel(const int* __restrict__ cnt, int* __restrict__ excl,
                             int* __restrict__ blockSums, int n) {
    __shared__ int s[SCAN_BLK];
    int t = threadIdx.x;
    int i = blockIdx.x * SCAN_BLK + t;
    int v = (i < n) ? cnt[i] : 0;
    s[t] = v;
    __syncthreads();
    for (int off = 1; off < SCAN_BLK; off <<= 1) {
        int add = (t >= off) ? s[t - off] : 0;
        __syncthreads();
        s[t] += add;
        __syncthreads();
    }
    if (i < n) excl[i] = s[t] - v;
    if (t == SCAN_BLK - 1) blockSums[blockIdx.x] = s[t];
}

// exclusive scan of block sums (nb <= 128), single block
__global__ void scan2_kernel(int* __restrict__ blockSums, int nb) {
    __shared__ int s[128];
    int t = threadIdx.x;
    s[t] = (t < nb) ? blockSums[t] : 0;
    __syncthreads();
    if (t == 0) {
        int run = 0;
        for (int k = 0; k < nb; ++k) { int v = s[k]; s[k] = run; run += v; }
    }
    __syncthreads();
    if (t < nb) blockSums[t] = s[t];
}

// finalize rowptr, init cursor, compute dinv = rsqrt(1 + indeg)
__global__ void scan3_kernel(const int* __restrict__ cnt, int* __restrict__ rowptr,
                             const int* __restrict__ blockSums, int* __restrict__ cursor,
                             float* __restrict__ dinv, int n, int ne) {
    int i = blockIdx.x * blockDim.x + threadIdx.x;
    if (i >= n) return;
    int rp = rowptr[i] + blockSums[i >> 10];
    rowptr[i] = rp;
    cursor[i] = rp;
    dinv[i] = rsqrtf((float)(cnt[i] + 1));
    if (i == 0) rowptr[n] = ne;
}

__global__ void fill_kernel(const int* __restrict__ src, const int* __restrict__ dst,
                            int* __restrict__ cursor, int* __restrict__ csr, int ne) {
    int e = blockIdx.x * blockDim.x + threadIdx.x;
    if (e >= ne) return;
    int d = dst[e];
    int pos = atomicAdd(&cursor[d], 1);
    csr[pos] = src[e];
}

// ---------------- H = dinv[row] * (relu?)(X) @ W ----------------
template<bool RELU>
__global__ void gemm64_kernel(const float* __restrict__ X, const float* __restrict__ W,
                              const float* __restrict__ dinv, float* __restrict__ H, int n) {
    __shared__ float Ws[NCH * NCH];
    int t = threadIdx.x;
    for (int i = t; i < NCH * NCH; i += blockDim.x) Ws[i] = W[i];
    __syncthreads();
    int row = blockIdx.x * blockDim.x + t;
    if (row >= n) return;
    const float4* xr = (const float4*)(X + (long long)row * NCH);
    float acc[NCH];
#pragma unroll
    for (int c = 0; c < NCH; ++c) acc[c] = 0.f;
#pragma unroll
    for (int k4 = 0; k4 < NCH / 4; ++k4) {
        float4 xv = xr[k4];
        if (RELU) {
            xv.x = fmaxf(xv.x, 0.f); xv.y = fmaxf(xv.y, 0.f);
            xv.z = fmaxf(xv.z, 0.f); xv.w = fmaxf(xv.w, 0.f);
        }
        float xs[4] = {xv.x, xv.y, xv.z, xv.w};
#pragma unroll
        for (int j = 0; j < 4; ++j) {
            int k = k4 * 4 + j;
#pragma unroll
            for (int c = 0; c < NCH; ++c)
                acc[c] = fmaf(xs[j], Ws[k * NCH + c], acc[c]);  // uniform LDS read -> broadcast
        }
    }
    float di = dinv[row];
    float4* hr = (float4*)(H + (long long)row * NCH);
#pragma unroll
    for (int c4 = 0; c4 < NCH / 4; ++c4)
        hr[c4] = make_float4(di * acc[4 * c4], di * acc[4 * c4 + 1],
                             di * acc[4 * c4 + 2], di * acc[4 * c4 + 3]);
}

// ---------------- out[d,:] = dinv[d] * (hs[d,:] + sum_{s in N(d)} hs[s,:]) + b ----------------
__global__ void agg_kernel(const float* __restrict__ hs, const int* __restrict__ rowptr,
                           const int* __restrict__ csr, const float* __restrict__ dinv,
                           const float* __restrict__ b, float* __restrict__ out, int n) {
    int wid = (blockIdx.x * blockDim.x + threadIdx.x) >> 6;   // one wave per node
    int lane = threadIdx.x & 63;                              // one lane per channel
    if (wid >= n) return;
    int start = rowptr[wid];
    int end = rowptr[wid + 1];
    float acc = hs[(long long)wid * NCH + lane];              // self-loop term
    int e = start;
    for (; e + 4 <= end; e += 4) {                            // 4 gathers in flight
        int s0 = csr[e], s1 = csr[e + 1], s2 = csr[e + 2], s3 = csr[e + 3];
        float a0 = hs[(long long)s0 * NCH + lane];
        float a1 = hs[(long long)s1 * NCH + lane];
        float a2 = hs[(long long)s2 * NCH + lane];
        float a3 = hs[(long long)s3 * NCH + lane];
        acc += (a0 + a1) + (a2 + a3);
    }
    for (; e < end; ++e) acc += hs[(long long)csr[e] * NCH + lane];
    out[(long long)wid * NCH + lane] = dinv[wid] * acc + b[lane];
}

extern "C" void kernel_launch(void* const* d_in, const int* in_sizes, int n_in,
                              void* d_out, int out_size, void* d_ws, size_t ws_size,
                              hipStream_t stream) {
    const float* x  = (const float*)d_in[0];
    const int*   ei = (const int*)d_in[1];
    const float* W1 = (const float*)d_in[2];
    const float* b1 = (const float*)d_in[3];
    const float* W2 = (const float*)d_in[4];
    const float* b2 = (const float*)d_in[5];
    const int n  = in_sizes[0] / NCH;   // 100000
    const int ne = in_sizes[1] / 2;     // 1600000
    const int* src = ei;
    const int* dst = ei + ne;
    float* out = (float*)d_out;

    // workspace layout (all 256B-aligned)
    char* ws = (char*)d_ws;
    size_t off = 0;
    auto alloc = [&](size_t bytes) { void* p = ws + off; off += (bytes + 255) & ~(size_t)255; return p; };
    int*   cnt       = (int*)alloc((size_t)n * 4);
    int*   rowptr    = (int*)alloc((size_t)(n + 1) * 4);
    int*   cursor    = (int*)alloc((size_t)n * 4);
    int*   blockSums = (int*)alloc(512);
    float* dinv      = (float*)alloc((size_t)n * 4);
    int*   csr       = (int*)alloc((size_t)ne * 4);
    float* bufA      = (float*)alloc((size_t)n * NCH * 4);   // h (scaled)
    // layer-1 aggregated output lives in d_out (overwritten by layer 2 at the end)

    const int blk = 256;
    const int gN  = (n + blk - 1) / blk;
    const int gE  = (ne + blk - 1) / blk;
    const int nb  = (n + SCAN_BLK - 1) / SCAN_BLK;           // 98
    const int gAgg = (n * 64 + blk - 1) / blk;               // wave per node

    // ---- CSR build (once, reused by both layers) ----
    zero_kernel<<<gN, blk, 0, stream>>>(cnt, n);
    hist_kernel<<<gE, blk, 0, stream>>>(dst, cnt, ne);
    scan1_kernel<<<nb, SCAN_BLK, 0, stream>>>(cnt, rowptr, blockSums, n);
    scan2_kernel<<<1, 128, 0, stream>>>(blockSums, nb);
    scan3_kernel<<<gN, blk, 0, stream>>>(cnt, rowptr, blockSums, cursor, dinv, n, ne);
    fill_kernel<<<gE, blk, 0, stream>>>(src, dst, cursor, csr, ne);

    // ---- layer 1 ----
    gemm64_kernel<false><<<gN, blk, 0, stream>>>(x, W1, dinv, bufA, n);
    agg_kernel<<<gAgg, blk, 0, stream>>>(bufA, rowptr, csr, dinv, b1, out, n);

    // ---- layer 2 (relu fused into GEMM load) ----
    gemm64_kernel<true><<<gN, blk, 0, stream>>>(out, W2, dinv, bufA, n);
    agg_kernel<<<gAgg, blk, 0, stream>>>(bufA, rowptr, csr, dinv, b2, out, n);
}